// Round 1
// baseline (759.971 us; speedup 1.0000x reference)
//
#include <hip/hip_runtime.h>
#include <hip/hip_bf16.h>
#include <cstdint>
#include <type_traits>

typedef __attribute__((ext_vector_type(8))) __bf16 bf16x8;
typedef __attribute__((ext_vector_type(8))) short short8;
typedef __attribute__((ext_vector_type(4))) float f32x4;
using u16 = unsigned short;

// ---- MFMA fragment-type autodetect (builtin wants v8bf16 on upstream clang,
// some toolchains used v8i16; SFINAE picks whichever type-checks) ----
template <typename T, typename = void> struct mfma_ok : std::false_type {};
template <typename T>
struct mfma_ok<T, std::void_t<decltype(__builtin_amdgcn_mfma_f32_16x16x32_bf16(
    std::declval<T>(), std::declval<T>(), std::declval<f32x4>(), 0, 0, 0))>>
    : std::true_type {};
using frag_t = std::conditional_t<mfma_ok<bf16x8>::value, bf16x8, short8>;
static_assert(sizeof(frag_t) == 16, "frag must be 4 VGPRs");

template <typename T>
__device__ __forceinline__ f32x4 MFMA(T a, T b, f32x4 c) {
  return __builtin_amdgcn_mfma_f32_16x16x32_bf16(a, b, c, 0, 0, 0);
}

__device__ __forceinline__ void gl_lds16(const u16* g, u16* l) {
  __builtin_amdgcn_global_load_lds(
      (const __attribute__((address_space(1))) unsigned int*)g,
      (__attribute__((address_space(3))) unsigned int*)l, 16, 0, 0);
}

__device__ __forceinline__ u16 f2bf(float v) {
  __hip_bfloat16 h = __float2bfloat16(v);
  return __builtin_bit_cast(u16, h);
}

// ---------------------------------------------------------------------------
// Core GEMM tile: 128 rows x 64 cols x NB B-matrices, BK=32, 256 threads
// (4 waves 2x2). A[row][k] (lda), B_q[col][k] (ldb, q*bstride apart).
// out = A·B^T accumulated into acc[q][fm][fn] (16x16x32 bf16 MFMA).
// ---------------------------------------------------------------------------
template <int NB>
__device__ __forceinline__ void gemm_core(
    const u16* __restrict__ A, int lda,
    const u16* __restrict__ B0, int ldb, int bstride, int K,
    u16* sA, u16* sB, f32x4 (&acc)[NB][4][2])
{
  const int t = threadIdx.x;
  const int l = t & 63;
  const int w = t >> 6;
  const int wm = w >> 1, wc = w & 1;

  // staging: wave w stages A-chunks (w*2+p)*1KB, B-chunks (q*4+w)*1KB
  const u16* gA0 = A + (w * 32 + (l >> 2)) * lda + (l & 3) * 8;
  const u16* gA1 = gA0 + 16 * lda;
  u16* lA0 = sA + (w * 2 + 0) * 512;
  u16* lA1 = sA + (w * 2 + 1) * 512;

  const u16* gB[NB];
  u16* lB[NB];
#pragma unroll
  for (int q = 0; q < NB; ++q) {
    gB[q] = B0 + q * bstride + (w * 16 + (l >> 2)) * ldb + (l & 3) * 8;
    lB[q] = sB + (q * 4 + w) * 512;
  }

  const int aoff0 = (wm * 64 + (l & 15)) * 32 + (l >> 4) * 8;
  const int boff0 = (wc * 32 + (l & 15)) * 32 + (l >> 4) * 8;

  const int nk = K >> 5;
  for (int ks = 0; ks < nk; ++ks) {
    gl_lds16(gA0, lA0);
    gl_lds16(gA1, lA1);
#pragma unroll
    for (int q = 0; q < NB; ++q) gl_lds16(gB[q], lB[q]);
    gA0 += 32; gA1 += 32;
#pragma unroll
    for (int q = 0; q < NB; ++q) gB[q] += 32;
    __syncthreads();   // compiler emits vmcnt(0) drain before s_barrier

    frag_t a[4];
#pragma unroll
    for (int fm = 0; fm < 4; ++fm)
      a[fm] = *(const frag_t*)(sA + aoff0 + fm * (16 * 32));
#pragma unroll
    for (int q = 0; q < NB; ++q) {
#pragma unroll
      for (int fn = 0; fn < 2; ++fn) {
        frag_t b = *(const frag_t*)(sB + q * 2048 + boff0 + fn * (16 * 32));
#pragma unroll
        for (int fm = 0; fm < 4; ++fm)
          acc[q][fm][fn] = MFMA(a[fm], b, acc[q][fm][fn]);
      }
    }
    __syncthreads();
  }
}

// ---------------------------------------------------------------------------
// Kernel 1: weight repack f32 -> bf16 (+padding)
// Wcat[4][1024][1024] order i,f,z,o ; Rcat[4][8][128][128] ; upcat[2][1408][1024];
// dnp[1024][1408] (k-padded)
// ---------------------------------------------------------------------------
__global__ __launch_bounds__(256) void prep_kernel(
    const float* __restrict__ Wi, const float* __restrict__ Wf,
    const float* __restrict__ Wz, const float* __restrict__ Wo,
    const float* __restrict__ Ri, const float* __restrict__ Rf,
    const float* __restrict__ Rz, const float* __restrict__ Ro,
    const float* __restrict__ upw, const float* __restrict__ dnw,
    u16* __restrict__ Wcat, u16* __restrict__ Rcat,
    u16* __restrict__ upcat, u16* __restrict__ dnp)
{
  const int stride = gridDim.x * 256;
  for (int i = blockIdx.x * 256 + threadIdx.x; i < 9043968; i += stride) {
    if (i < 4194304) {
      const int gsel = i >> 20, r = i & 1048575;
      const float* W = (gsel == 0) ? Wi : (gsel == 1) ? Wf : (gsel == 2) ? Wz : Wo;
      Wcat[i] = f2bf(W[r]);
    } else if (i < 4718592) {
      const int j = i - 4194304;
      const int gsel = j >> 17, r = j & 131071;
      const float* R = (gsel == 0) ? Ri : (gsel == 1) ? Rf : (gsel == 2) ? Rz : Ro;
      Rcat[j] = f2bf(R[r]);
    } else if (i < 7602176) {
      const int j = i - 4718592;
      const int half = (j >= 1441792) ? 1 : 0;
      const int rem = j - half * 1441792;
      const int rrow = rem >> 10, k = rem & 1023;
      upcat[j] = (rrow < 1365) ? f2bf(upw[(half * 1365 + rrow) * 1024 + k]) : (u16)0;
    } else {
      const int j = i - 7602176;
      const int rrow = j / 1408, k = j - rrow * 1408;
      dnp[j] = (k < 1365) ? f2bf(dnw[rrow * 1365 + k]) : (u16)0;
    }
  }
}

// ---------------------------------------------------------------------------
// Kernel 2: LayerNorm(seq) -> x bf16 ; h0 -> bf16. One row per block.
// ---------------------------------------------------------------------------
__global__ __launch_bounds__(256) void ln_kernel(
    const float* __restrict__ seq, const float* __restrict__ h0,
    const float* __restrict__ lnw, const float* __restrict__ lnb,
    u16* __restrict__ xb, u16* __restrict__ h0b)
{
  const int row = blockIdx.x;
  const int t = threadIdx.x;
  const float4 v = ((const float4*)(seq + (size_t)row * 1024))[t];
  float s = v.x + v.y + v.z + v.w;
  float q = v.x * v.x + v.y * v.y + v.z * v.z + v.w * v.w;
#pragma unroll
  for (int o = 32; o >= 1; o >>= 1) { s += __shfl_xor(s, o); q += __shfl_xor(q, o); }
  __shared__ float sm[8];
  const int l = t & 63, w = t >> 6;
  if (l == 0) { sm[w] = s; sm[4 + w] = q; }
  __syncthreads();
  s = sm[0] + sm[1] + sm[2] + sm[3];
  q = sm[4] + sm[5] + sm[6] + sm[7];
  const float mu = s * (1.f / 1024.f);
  const float var = q * (1.f / 1024.f) - mu * mu;
  const float rstd = rsqrtf(var + 1e-5f);
  const float4 wv = ((const float4*)lnw)[t];
  const float4 bv = ((const float4*)lnb)[t];
  ushort4 o4;
  o4.x = f2bf((v.x - mu) * rstd * wv.x + bv.x);
  o4.y = f2bf((v.y - mu) * rstd * wv.y + bv.y);
  o4.z = f2bf((v.z - mu) * rstd * wv.z + bv.z);
  o4.w = f2bf((v.w - mu) * rstd * wv.w + bv.w);
  ((ushort4*)(xb + (size_t)row * 1024))[t] = o4;
  const float4 h = ((const float4*)(h0 + (size_t)row * 1024))[t];
  ushort4 h4;
  h4.x = f2bf(h.x); h4.y = f2bf(h.y); h4.z = f2bf(h.z); h4.w = f2bf(h.w);
  ((ushort4*)(h0b + (size_t)row * 1024))[t] = h4;
}

// ---------------------------------------------------------------------------
// Kernel 3: fused 4-gate GEMM (+recurrent block-diag term) + sLSTM pointwise.
// Tile: 128 rows x 64 cols, all 4 gates accumulated; writes c,n,h,m (f32).
// ---------------------------------------------------------------------------
__global__ __launch_bounds__(256) void gate_kernel(
    const u16* __restrict__ xb, const u16* __restrict__ h0b,
    const u16* __restrict__ Wcat, const u16* __restrict__ Rcat,
    const float* __restrict__ bi, const float* __restrict__ bfv,
    const float* __restrict__ bz, const float* __restrict__ bo,
    const float* __restrict__ c0, const float* __restrict__ n0i,
    const float* __restrict__ m0,
    float* __restrict__ oc, float* __restrict__ on,
    float* __restrict__ oh, float* __restrict__ om)
{
  __shared__ __align__(16) u16 sA[128 * 32];
  __shared__ __align__(16) u16 sB[4 * 64 * 32];
  const int n0c = blockIdx.x * 64;
  const int m0r = blockIdx.y * 128;
  f32x4 acc[4][4][2] = {};
  // x @ W^T  (K=1024)
  gemm_core<4>(xb + m0r * 1024, 1024, Wcat + n0c * 1024, 1024, 1 << 20, 1024,
               sA, sB, acc);
  // + blockdiag(h0 @ R^T)  (K=128, one head per 64-col tile)
  const int head = n0c >> 7;
  gemm_core<4>(h0b + m0r * 1024 + head * 128, 1024,
               Rcat + head * 16384 + (n0c & 127) * 128, 128, 131072, 128,
               sA, sB, acc);

  const int t = threadIdx.x, l = t & 63, w = t >> 6, wm = w >> 1, wc = w & 1;
#pragma unroll
  for (int fm = 0; fm < 4; ++fm) {
#pragma unroll
    for (int fn = 0; fn < 2; ++fn) {
      const int cc = n0c + wc * 32 + fn * 16 + (l & 15);
      const float biv = bi[cc], bfvvv = bfv[cc], bzv = bz[cc], bov = bo[cc];
#pragma unroll
      for (int r = 0; r < 4; ++r) {
        const int row = m0r + wm * 64 + fm * 16 + (l >> 4) * 4 + r;
        const int idx = row * 1024 + cc;
        const float it = acc[0][fm][fn][r] + biv;
        const float ft = acc[1][fm][fn][r] + bfvvv;
        const float zt = acc[2][fm][fn][r] + bzv;
        const float ot = acc[3][fm][fn][r] + bov;
        const float mp = m0[idx];
        const float mt = fmaxf(ft + mp, it);
        const float ie = __expf(it - mt);
        const float fe = __expf(ft - mt + mp);
        const float ct = fe * c0[idx] + ie * tanhf(zt);
        const float nt = fe * n0i[idx] + ie;
        const float ht = (ct / nt) / (1.f + __expf(-ot));
        oc[idx] = ct; on[idx] = nt; oh[idx] = ht; om[idx] = mt;
      }
    }
  }
}

// ---------------------------------------------------------------------------
// Kernel 4: GroupNorm over heads (128 ch / group), one wave per group -> bf16
// ---------------------------------------------------------------------------
__global__ __launch_bounds__(256) void gn_kernel(
    const float* __restrict__ h, const float* __restrict__ gw,
    const float* __restrict__ gb, u16* __restrict__ gnb)
{
  const int t = threadIdx.x, l = t & 63, w = t >> 6;
  for (int grp = blockIdx.x * 4 + w; grp < 16384 * 8; grp += gridDim.x * 4) {
    const int b = grp >> 3, hd = grp & 7;
    const float2 v = ((const float2*)(h + b * 1024 + hd * 128))[l];
    float s = v.x + v.y, q = v.x * v.x + v.y * v.y;
#pragma unroll
    for (int o = 32; o >= 1; o >>= 1) { s += __shfl_xor(s, o); q += __shfl_xor(q, o); }
    const float mu = s * (1.f / 128.f);
    const float var = q * (1.f / 128.f) - mu * mu;
    const float rstd = rsqrtf(var + 1e-5f);
    const float2 wv = ((const float2*)(gw + hd * 128))[l];
    const float2 bv = ((const float2*)(gb + hd * 128))[l];
    ushort2 o2;
    o2.x = f2bf((v.x - mu) * rstd * wv.x + bv.x);
    o2.y = f2bf((v.y - mu) * rstd * wv.y + bv.y);
    ((ushort2*)(gnb + b * 1024 + hd * 128))[l] = o2;
  }
}

// ---------------------------------------------------------------------------
// Kernel 5: up-proj, dual accumulators (w1,w2) + exact-GELU glu epilogue -> bf16
// N padded to 1408 (pad cols produce exact 0)
// ---------------------------------------------------------------------------
__global__ __launch_bounds__(256) void up_kernel(
    const u16* __restrict__ gnb, const u16* __restrict__ upcat,
    const float* __restrict__ upb, u16* __restrict__ g)
{
  __shared__ __align__(16) u16 sA[128 * 32];
  __shared__ __align__(16) u16 sB[2 * 64 * 32];
  const int n0c = blockIdx.x * 64;
  const int m0r = blockIdx.y * 128;
  f32x4 acc[2][4][2] = {};
  gemm_core<2>(gnb + m0r * 1024, 1024, upcat + n0c * 1024, 1024, 1441792, 1024,
               sA, sB, acc);
  const int t = threadIdx.x, l = t & 63, w = t >> 6, wm = w >> 1, wc = w & 1;
#pragma unroll
  for (int fm = 0; fm < 4; ++fm) {
#pragma unroll
    for (int fn = 0; fn < 2; ++fn) {
      const int cc = n0c + wc * 32 + fn * 16 + (l & 15);
      const float b1 = (cc < 1365) ? upb[cc] : 0.f;
      const float b2 = (cc < 1365) ? upb[1365 + cc] : 0.f;
#pragma unroll
      for (int r = 0; r < 4; ++r) {
        const int row = m0r + wm * 64 + fm * 16 + (l >> 4) * 4 + r;
        const float u1 = acc[0][fm][fn][r] + b1;
        const float u2 = acc[1][fm][fn][r] + b2;
        const float ge = 0.5f * u2 * (1.f + erff(u2 * 0.70710678118654752f));
        g[row * 1408 + cc] = f2bf(u1 + ge);
      }
    }
  }
}

// ---------------------------------------------------------------------------
// Kernel 6: down-proj (K=1408, zero-padded) + bias + residual -> d_out
// ---------------------------------------------------------------------------
__global__ __launch_bounds__(256) void down_kernel(
    const u16* __restrict__ g, const u16* __restrict__ dnp,
    const float* __restrict__ dnb, const float* __restrict__ seq,
    float* __restrict__ out)
{
  __shared__ __align__(16) u16 sA[128 * 32];
  __shared__ __align__(16) u16 sB[1 * 64 * 32];
  const int n0c = blockIdx.x * 64;
  const int m0r = blockIdx.y * 128;
  f32x4 acc[1][4][2] = {};
  gemm_core<1>(g + m0r * 1408, 1408, dnp + n0c * 1408, 1408, 0, 1408,
               sA, sB, acc);
  const int t = threadIdx.x, l = t & 63, w = t >> 6, wm = w >> 1, wc = w & 1;
#pragma unroll
  for (int fm = 0; fm < 4; ++fm) {
#pragma unroll
    for (int fn = 0; fn < 2; ++fn) {
      const int cc = n0c + wc * 32 + fn * 16 + (l & 15);
      const float bb = dnb[cc];
#pragma unroll
      for (int r = 0; r < 4; ++r) {
        const int row = m0r + wm * 64 + fm * 16 + (l >> 4) * 4 + r;
        const int idx = row * 1024 + cc;
        out[idx] = acc[0][fm][fn][r] + bb + seq[idx];
      }
    }
  }
}

// ---------------------------------------------------------------------------
extern "C" void kernel_launch(void* const* d_in, const int* in_sizes, int n_in,
                              void* d_out, int out_size, void* d_ws, size_t ws_size,
                              hipStream_t stream) {
  const float* seq = (const float*)d_in[0];
  const float* c0  = (const float*)d_in[1];
  const float* n0i = (const float*)d_in[2];
  const float* h0  = (const float*)d_in[3];
  const float* m0  = (const float*)d_in[4];
  const float* lnw = (const float*)d_in[5];
  const float* lnb = (const float*)d_in[6];
  const float* Wz  = (const float*)d_in[7];
  const float* bz  = (const float*)d_in[8];
  const float* Wi  = (const float*)d_in[9];
  const float* bi  = (const float*)d_in[10];
  const float* Wo  = (const float*)d_in[11];
  const float* bo  = (const float*)d_in[12];
  const float* Wf  = (const float*)d_in[13];
  const float* bf_ = (const float*)d_in[14];
  const float* Rz  = (const float*)d_in[15];
  const float* Ri  = (const float*)d_in[16];
  const float* Ro  = (const float*)d_in[17];
  const float* Rf  = (const float*)d_in[18];
  const float* gw  = (const float*)d_in[19];
  const float* gb  = (const float*)d_in[20];
  const float* upw = (const float*)d_in[21];
  const float* upb = (const float*)d_in[22];
  const float* dnw = (const float*)d_in[23];
  const float* dnb = (const float*)d_in[24];

  char* ws = (char*)d_ws;
  u16* xb   = (u16*)(ws);              // 33,554,432 B (reused for gn output)
  u16* h0b  = (u16*)(ws + 33554432);   // 33,554,432 B
  u16* Wcat = (u16*)(ws + 67108864);   //  8,388,608 B
  u16* Rcat = (u16*)(ws + 75497472);   //  1,048,576 B
  u16* upc  = (u16*)(ws + 76546048);   //  5,767,168 B
  u16* dnp  = (u16*)(ws + 82313216);   //  2,883,584 B
  u16* g    = (u16*)(ws + 85196800);   // 46,137,344 B  -> total 131,334,144 B

  float* out = (float*)d_out;
  float* oc = out + 16777216;
  float* on = out + 2 * 16777216;
  float* oh = out + 3 * 16777216;
  float* om = out + 4 * 16777216;

  prep_kernel<<<dim3(2048), dim3(256), 0, stream>>>(
      Wi, Wf, Wz, Wo, Ri, Rf, Rz, Ro, upw, dnw, Wcat, Rcat, upc, dnp);
  ln_kernel<<<dim3(16384), dim3(256), 0, stream>>>(seq, h0, lnw, lnb, xb, h0b);
  gate_kernel<<<dim3(16, 128), dim3(256), 0, stream>>>(
      xb, h0b, Wcat, Rcat, bi, bf_, bz, bo, c0, n0i, m0, oc, on, oh, om);
  gn_kernel<<<dim3(2048), dim3(256), 0, stream>>>(oh, gw, gb, xb);
  up_kernel<<<dim3(22, 128), dim3(256), 0, stream>>>(xb, upc, upb, g);
  down_kernel<<<dim3(16, 128), dim3(256), 0, stream>>>(g, dnp, dnb, seq, out);
}

// Round 2
// 575.952 us; speedup vs baseline: 1.3195x; 1.3195x over previous
//
#include <hip/hip_runtime.h>
#include <hip/hip_bf16.h>
#include <cstdint>
#include <type_traits>

typedef __attribute__((ext_vector_type(8))) __bf16 bf16x8;
typedef __attribute__((ext_vector_type(8))) short short8;
typedef __attribute__((ext_vector_type(4))) float f32x4;
using u16 = unsigned short;

// ---- MFMA fragment-type autodetect ----
template <typename T, typename = void> struct mfma_ok : std::false_type {};
template <typename T>
struct mfma_ok<T, std::void_t<decltype(__builtin_amdgcn_mfma_f32_16x16x32_bf16(
    std::declval<T>(), std::declval<T>(), std::declval<f32x4>(), 0, 0, 0))>>
    : std::true_type {};
using frag_t = std::conditional_t<mfma_ok<bf16x8>::value, bf16x8, short8>;
static_assert(sizeof(frag_t) == 16, "frag must be 4 VGPRs");

template <typename T>
__device__ __forceinline__ f32x4 MFMA(T a, T b, f32x4 c) {
  return __builtin_amdgcn_mfma_f32_16x16x32_bf16(a, b, c, 0, 0, 0);
}

__device__ __forceinline__ void gl_lds16(const u16* g, u16* l) {
  __builtin_amdgcn_global_load_lds(
      (const __attribute__((address_space(1))) unsigned int*)g,
      (__attribute__((address_space(3))) unsigned int*)l, 16, 0, 0);
}

__device__ __forceinline__ u16 f2bf(float v) {
  __hip_bfloat16 h = __float2bfloat16(v);
  return __builtin_bit_cast(u16, h);
}

// ---------------------------------------------------------------------------
// Core GEMM tile v2: 512 threads / 8 waves, wave grid 4(rows)x2(cols).
// Block tile: 128 rows x (NB x 64) cols, BK=32. Per-wave acc[NB][2][2]
// (NB*16 f32x4 = NB*16 regs... 64 VGPRs at NB=4). LDS layout linear for
// global_load_lds; bank-conflict fix via chunk swizzle kc ^= (row>>1)&3
// applied to BOTH the global source address and the ds_read offset (rule 21).
// A[row][k] row-major (lda); B_q[col][k] row-major (ldb), q*bstride apart.
// ---------------------------------------------------------------------------
template <int NB>
__device__ __forceinline__ void gemm_core(
    const u16* __restrict__ A, int lda,
    const u16* __restrict__ B0, int ldb, int bstride, int K,
    u16* sA, u16* sB, f32x4 (&acc)[NB][2][2])
{
  static_assert(NB % 2 == 0, "NB must be even");
  const int t = threadIdx.x;          // 0..511
  const int l = t & 63;
  const int w = t >> 6;               // 0..7
  const int wm = w >> 1, wc = w & 1;  // 4x2 wave grid

  // ---- staging addresses (source pre-swizzled, LDS dest linear) ----
  const int kcs = (t & 3) ^ ((t >> 3) & 3);   // swizzled 16B chunk within row
  const u16* gA = A + (t >> 2) * lda + kcs * 8;
  u16* lA = sA + w * 512;                     // + lane*16B by HW

  const u16* gB[NB / 2];
  u16* lB[NB / 2];
#pragma unroll
  for (int j = 0; j < NB / 2; ++j) {
    const int q = 2 * j + (t >> 8);
    gB[j] = B0 + q * bstride + ((t >> 2) & 63) * ldb + kcs * 8;
    lB[j] = sB + j * 4096 + w * 512;
  }

  // ---- fragment read offsets (same involution on kc) ----
  const int kc = l >> 4;
  int aoff[2], boff[2];
#pragma unroll
  for (int f = 0; f < 2; ++f) {
    const int ar = wm * 32 + f * 16 + (l & 15);
    aoff[f] = ar * 32 + (kc ^ ((ar >> 1) & 3)) * 8;
    const int br = wc * 32 + f * 16 + (l & 15);
    boff[f] = br * 32 + (kc ^ ((br >> 1) & 3)) * 8;
  }

  const int nk = K >> 5;
  for (int ks = 0; ks < nk; ++ks) {
    gl_lds16(gA, lA);
#pragma unroll
    for (int j = 0; j < NB / 2; ++j) gl_lds16(gB[j], lB[j]);
    gA += 32;
#pragma unroll
    for (int j = 0; j < NB / 2; ++j) gB[j] += 32;
    __syncthreads();

    frag_t a[2];
#pragma unroll
    for (int fm = 0; fm < 2; ++fm) a[fm] = *(const frag_t*)(sA + aoff[fm]);
#pragma unroll
    for (int q = 0; q < NB; ++q) {
#pragma unroll
      for (int fn = 0; fn < 2; ++fn) {
        frag_t b = *(const frag_t*)(sB + q * 2048 + boff[fn]);
#pragma unroll
        for (int fm = 0; fm < 2; ++fm)
          acc[q][fm][fn] = MFMA(a[fm], b, acc[q][fm][fn]);
      }
    }
    __syncthreads();
  }
}

// bijective XCD swizzle (nwg % 8 == 0 for all our grids)
__device__ __forceinline__ int xcd_swz(int wid, int nwg) {
  return (wid & 7) * (nwg >> 3) + (wid >> 3);
}

// ---------------------------------------------------------------------------
// Kernel 1: weight repack f32 -> bf16 (+padding)
// ---------------------------------------------------------------------------
__global__ __launch_bounds__(256) void prep_kernel(
    const float* __restrict__ Wi, const float* __restrict__ Wf,
    const float* __restrict__ Wz, const float* __restrict__ Wo,
    const float* __restrict__ Ri, const float* __restrict__ Rf,
    const float* __restrict__ Rz, const float* __restrict__ Ro,
    const float* __restrict__ upw, const float* __restrict__ dnw,
    u16* __restrict__ Wcat, u16* __restrict__ Rcat,
    u16* __restrict__ upcat, u16* __restrict__ dnp)
{
  const int stride = gridDim.x * 256;
  for (int i = blockIdx.x * 256 + threadIdx.x; i < 9043968; i += stride) {
    if (i < 4194304) {
      const int gsel = i >> 20, r = i & 1048575;
      const float* W = (gsel == 0) ? Wi : (gsel == 1) ? Wf : (gsel == 2) ? Wz : Wo;
      Wcat[i] = f2bf(W[r]);
    } else if (i < 4718592) {
      const int j = i - 4194304;
      const int gsel = j >> 17, r = j & 131071;
      const float* R = (gsel == 0) ? Ri : (gsel == 1) ? Rf : (gsel == 2) ? Rz : Ro;
      Rcat[j] = f2bf(R[r]);
    } else if (i < 7602176) {
      const int j = i - 4718592;
      const int half = (j >= 1441792) ? 1 : 0;
      const int rem = j - half * 1441792;
      const int rrow = rem >> 10, k = rem & 1023;
      upcat[j] = (rrow < 1365) ? f2bf(upw[(half * 1365 + rrow) * 1024 + k]) : (u16)0;
    } else {
      const int j = i - 7602176;
      const int rrow = j / 1408, k = j - rrow * 1408;
      dnp[j] = (k < 1365) ? f2bf(dnw[rrow * 1365 + k]) : (u16)0;
    }
  }
}

// ---------------------------------------------------------------------------
// Kernel 2: LayerNorm(seq) -> x bf16 ; h0 -> bf16. One row per block.
// ---------------------------------------------------------------------------
__global__ __launch_bounds__(256) void ln_kernel(
    const float* __restrict__ seq, const float* __restrict__ h0,
    const float* __restrict__ lnw, const float* __restrict__ lnb,
    u16* __restrict__ xb, u16* __restrict__ h0b)
{
  const int row = blockIdx.x;
  const int t = threadIdx.x;
  const float4 v = ((const float4*)(seq + (size_t)row * 1024))[t];
  float s = v.x + v.y + v.z + v.w;
  float q = v.x * v.x + v.y * v.y + v.z * v.z + v.w * v.w;
#pragma unroll
  for (int o = 32; o >= 1; o >>= 1) { s += __shfl_xor(s, o); q += __shfl_xor(q, o); }
  __shared__ float sm[8];
  const int l = t & 63, w = t >> 6;
  if (l == 0) { sm[w] = s; sm[4 + w] = q; }
  __syncthreads();
  s = sm[0] + sm[1] + sm[2] + sm[3];
  q = sm[4] + sm[5] + sm[6] + sm[7];
  const float mu = s * (1.f / 1024.f);
  const float var = q * (1.f / 1024.f) - mu * mu;
  const float rstd = rsqrtf(var + 1e-5f);
  const float4 wv = ((const float4*)lnw)[t];
  const float4 bv = ((const float4*)lnb)[t];
  ushort4 o4;
  o4.x = f2bf((v.x - mu) * rstd * wv.x + bv.x);
  o4.y = f2bf((v.y - mu) * rstd * wv.y + bv.y);
  o4.z = f2bf((v.z - mu) * rstd * wv.z + bv.z);
  o4.w = f2bf((v.w - mu) * rstd * wv.w + bv.w);
  ((ushort4*)(xb + (size_t)row * 1024))[t] = o4;
  const float4 h = ((const float4*)(h0 + (size_t)row * 1024))[t];
  ushort4 h4;
  h4.x = f2bf(h.x); h4.y = f2bf(h.y); h4.z = f2bf(h.z); h4.w = f2bf(h.w);
  ((ushort4*)(h0b + (size_t)row * 1024))[t] = h4;
}

// ---------------------------------------------------------------------------
// Kernel 3: fused 4-gate GEMM (+recurrent block-diag term) + sLSTM pointwise.
// Tile 128 rows x 64 cols (x4 gates); writes c,n,h,m (f32).
// ---------------------------------------------------------------------------
__global__ __launch_bounds__(512) void gate_kernel(
    const u16* __restrict__ xb, const u16* __restrict__ h0b,
    const u16* __restrict__ Wcat, const u16* __restrict__ Rcat,
    const float* __restrict__ bi, const float* __restrict__ bfv,
    const float* __restrict__ bz, const float* __restrict__ bo,
    const float* __restrict__ c0, const float* __restrict__ n0i,
    const float* __restrict__ m0,
    float* __restrict__ oc, float* __restrict__ on,
    float* __restrict__ oh, float* __restrict__ om)
{
  __shared__ __align__(16) u16 sA[128 * 32];
  __shared__ __align__(16) u16 sB[4 * 64 * 32];
  const int wid = xcd_swz(blockIdx.x, 2048);
  const int n0c = (wid & 15) * 64;
  const int m0r = (wid >> 4) * 128;
  f32x4 acc[4][2][2] = {};
  // x @ W^T  (K=1024)
  gemm_core<4>(xb + m0r * 1024, 1024, Wcat + n0c * 1024, 1024, 1 << 20, 1024,
               sA, sB, acc);
  // + blockdiag(h0 @ R^T)  (K=128, one head per 64-col tile)
  const int head = n0c >> 7;
  gemm_core<4>(h0b + m0r * 1024 + head * 128, 1024,
               Rcat + head * 16384 + (n0c & 127) * 128, 128, 131072, 128,
               sA, sB, acc);

  const int t = threadIdx.x, l = t & 63, w = t >> 6, wm = w >> 1, wc = w & 1;
#pragma unroll
  for (int fm = 0; fm < 2; ++fm) {
#pragma unroll
    for (int fn = 0; fn < 2; ++fn) {
      const int cc = n0c + wc * 32 + fn * 16 + (l & 15);
      const float biv = bi[cc], bfvv = bfv[cc], bzv = bz[cc], bov = bo[cc];
      const int rbase = m0r + wm * 32 + fm * 16 + (l >> 4) * 4;
#pragma unroll
      for (int r = 0; r < 4; ++r) {
        const int idx = (rbase + r) * 1024 + cc;
        const float it = acc[0][fm][fn][r] + biv;
        const float ft = acc[1][fm][fn][r] + bfvv;
        const float zt = acc[2][fm][fn][r] + bzv;
        const float ot = acc[3][fm][fn][r] + bov;
        const float mp = m0[idx];
        const float mt = fmaxf(ft + mp, it);
        const float ie = __expf(it - mt);
        const float fe = __expf(ft - mt + mp);
        const float ct = fe * c0[idx] + ie * tanhf(zt);
        const float nt = fe * n0i[idx] + ie;
        const float ht = (ct / nt) / (1.f + __expf(-ot));
        oc[idx] = ct; on[idx] = nt; oh[idx] = ht; om[idx] = mt;
      }
    }
  }
}

// ---------------------------------------------------------------------------
// Kernel 4: GroupNorm over heads (128 ch / group), one wave per group -> bf16
// ---------------------------------------------------------------------------
__global__ __launch_bounds__(256) void gn_kernel(
    const float* __restrict__ h, const float* __restrict__ gw,
    const float* __restrict__ gb, u16* __restrict__ gnb)
{
  const int t = threadIdx.x, l = t & 63, w = t >> 6;
  for (int grp = blockIdx.x * 4 + w; grp < 16384 * 8; grp += gridDim.x * 4) {
    const int b = grp >> 3, hd = grp & 7;
    const float2 v = ((const float2*)(h + b * 1024 + hd * 128))[l];
    float s = v.x + v.y, q = v.x * v.x + v.y * v.y;
#pragma unroll
    for (int o = 32; o >= 1; o >>= 1) { s += __shfl_xor(s, o); q += __shfl_xor(q, o); }
    const float mu = s * (1.f / 128.f);
    const float var = q * (1.f / 128.f) - mu * mu;
    const float rstd = rsqrtf(var + 1e-5f);
    const float2 wv = ((const float2*)(gw + hd * 128))[l];
    const float2 bv = ((const float2*)(gb + hd * 128))[l];
    ushort2 o2;
    o2.x = f2bf((v.x - mu) * rstd * wv.x + bv.x);
    o2.y = f2bf((v.y - mu) * rstd * wv.y + bv.y);
    ((ushort2*)(gnb + b * 1024 + hd * 128))[l] = o2;
  }
}

// ---------------------------------------------------------------------------
// Kernel 5: up-proj, dual accumulators (w1,w2) + exact-GELU glu epilogue -> bf16
// ---------------------------------------------------------------------------
__global__ __launch_bounds__(512) void up_kernel(
    const u16* __restrict__ gnb, const u16* __restrict__ upcat,
    const float* __restrict__ upb, u16* __restrict__ g)
{
  __shared__ __align__(16) u16 sA[128 * 32];
  __shared__ __align__(16) u16 sB[2 * 64 * 32];
  const int wid = xcd_swz(blockIdx.x, 2816);
  const int bx = wid % 22, by = wid / 22;
  const int n0c = bx * 64;
  const int m0r = by * 128;
  f32x4 acc[2][2][2] = {};
  gemm_core<2>(gnb + m0r * 1024, 1024, upcat + n0c * 1024, 1024, 1441792, 1024,
               sA, sB, acc);
  const int t = threadIdx.x, l = t & 63, w = t >> 6, wm = w >> 1, wc = w & 1;
#pragma unroll
  for (int fm = 0; fm < 2; ++fm) {
#pragma unroll
    for (int fn = 0; fn < 2; ++fn) {
      const int cc = n0c + wc * 32 + fn * 16 + (l & 15);
      const float b1 = (cc < 1365) ? upb[cc] : 0.f;
      const float b2 = (cc < 1365) ? upb[1365 + cc] : 0.f;
      const int rbase = m0r + wm * 32 + fm * 16 + (l >> 4) * 4;
#pragma unroll
      for (int r = 0; r < 4; ++r) {
        const float u1 = acc[0][fm][fn][r] + b1;
        const float u2 = acc[1][fm][fn][r] + b2;
        const float ge = 0.5f * u2 * (1.f + erff(u2 * 0.70710678118654752f));
        g[(rbase + r) * 1408 + cc] = f2bf(u1 + ge);
      }
    }
  }
}

// ---------------------------------------------------------------------------
// Kernel 6: down-proj (K=1408, zero-padded) + bias + residual -> d_out
// NB=2 trick: two adjacent 64-col strips -> 128-col tile.
// ---------------------------------------------------------------------------
__global__ __launch_bounds__(512) void down_kernel(
    const u16* __restrict__ g, const u16* __restrict__ dnp,
    const float* __restrict__ dnb, const float* __restrict__ seq,
    float* __restrict__ out)
{
  __shared__ __align__(16) u16 sA[128 * 32];
  __shared__ __align__(16) u16 sB[2 * 64 * 32];
  const int wid = xcd_swz(blockIdx.x, 1024);
  const int n0c = (wid & 7) * 128;
  const int m0r = (wid >> 3) * 128;
  f32x4 acc[2][2][2] = {};
  gemm_core<2>(g + m0r * 1408, 1408, dnp + n0c * 1408, 1408, 64 * 1408, 1408,
               sA, sB, acc);
  const int t = threadIdx.x, l = t & 63, w = t >> 6, wm = w >> 1, wc = w & 1;
#pragma unroll
  for (int q = 0; q < 2; ++q) {
#pragma unroll
    for (int fm = 0; fm < 2; ++fm) {
#pragma unroll
      for (int fn = 0; fn < 2; ++fn) {
        const int cc = n0c + q * 64 + wc * 32 + fn * 16 + (l & 15);
        const float bb = dnb[cc];
        const int rbase = m0r + wm * 32 + fm * 16 + (l >> 4) * 4;
#pragma unroll
        for (int r = 0; r < 4; ++r) {
          const int idx = (rbase + r) * 1024 + cc;
          out[idx] = acc[q][fm][fn][r] + bb + seq[idx];
        }
      }
    }
  }
}

// ---------------------------------------------------------------------------
extern "C" void kernel_launch(void* const* d_in, const int* in_sizes, int n_in,
                              void* d_out, int out_size, void* d_ws, size_t ws_size,
                              hipStream_t stream) {
  const float* seq = (const float*)d_in[0];
  const float* c0  = (const float*)d_in[1];
  const float* n0i = (const float*)d_in[2];
  const float* h0  = (const float*)d_in[3];
  const float* m0  = (const float*)d_in[4];
  const float* lnw = (const float*)d_in[5];
  const float* lnb = (const float*)d_in[6];
  const float* Wz  = (const float*)d_in[7];
  const float* bz  = (const float*)d_in[8];
  const float* Wi  = (const float*)d_in[9];
  const float* bi  = (const float*)d_in[10];
  const float* Wo  = (const float*)d_in[11];
  const float* bo  = (const float*)d_in[12];
  const float* Wf  = (const float*)d_in[13];
  const float* bf_ = (const float*)d_in[14];
  const float* Rz  = (const float*)d_in[15];
  const float* Ri  = (const float*)d_in[16];
  const float* Ro  = (const float*)d_in[17];
  const float* Rf  = (const float*)d_in[18];
  const float* gw  = (const float*)d_in[19];
  const float* gb  = (const float*)d_in[20];
  const float* upw = (const float*)d_in[21];
  const float* upb = (const float*)d_in[22];
  const float* dnw = (const float*)d_in[23];
  const float* dnb = (const float*)d_in[24];

  char* ws = (char*)d_ws;
  u16* xb   = (u16*)(ws);              // 33,554,432 B (reused for gn output)
  u16* h0b  = (u16*)(ws + 33554432);   // 33,554,432 B
  u16* Wcat = (u16*)(ws + 67108864);   //  8,388,608 B
  u16* Rcat = (u16*)(ws + 75497472);   //  1,048,576 B
  u16* upc  = (u16*)(ws + 76546048);   //  5,767,168 B
  u16* dnp  = (u16*)(ws + 82313216);   //  2,883,584 B
  u16* g    = (u16*)(ws + 85196800);   // 46,137,344 B

  float* out = (float*)d_out;
  float* oc = out + 16777216;
  float* on = out + 2 * 16777216;
  float* oh = out + 3 * 16777216;
  float* om = out + 4 * 16777216;

  prep_kernel<<<dim3(2048), dim3(256), 0, stream>>>(
      Wi, Wf, Wz, Wo, Ri, Rf, Rz, Ro, upw, dnw, Wcat, Rcat, upc, dnp);
  ln_kernel<<<dim3(16384), dim3(256), 0, stream>>>(seq, h0, lnw, lnb, xb, h0b);
  gate_kernel<<<dim3(2048), dim3(512), 0, stream>>>(
      xb, h0b, Wcat, Rcat, bi, bf_, bz, bo, c0, n0i, m0, oc, on, oh, om);
  gn_kernel<<<dim3(2048), dim3(256), 0, stream>>>(oh, gw, gb, xb);
  up_kernel<<<dim3(2816), dim3(512), 0, stream>>>(xb, upc, upb, g);
  down_kernel<<<dim3(1024), dim3(512), 0, stream>>>(g, dnp, dnb, seq, out);
}

// Round 3
// 533.790 us; speedup vs baseline: 1.4237x; 1.0790x over previous
//
#include <hip/hip_runtime.h>
#include <hip/hip_bf16.h>
#include <cstdint>
#include <type_traits>

typedef __attribute__((ext_vector_type(8))) __bf16 bf16x8;
typedef __attribute__((ext_vector_type(8))) short short8;
typedef __attribute__((ext_vector_type(4))) float f32x4;
using u16 = unsigned short;

// ---- MFMA fragment-type autodetect ----
template <typename T, typename = void> struct mfma_ok : std::false_type {};
template <typename T>
struct mfma_ok<T, std::void_t<decltype(__builtin_amdgcn_mfma_f32_16x16x32_bf16(
    std::declval<T>(), std::declval<T>(), std::declval<f32x4>(), 0, 0, 0))>>
    : std::true_type {};
using frag_t = std::conditional_t<mfma_ok<bf16x8>::value, bf16x8, short8>;
static_assert(sizeof(frag_t) == 16, "frag must be 4 VGPRs");

template <typename T>
__device__ __forceinline__ f32x4 MFMA(T a, T b, f32x4 c) {
  return __builtin_amdgcn_mfma_f32_16x16x32_bf16(a, b, c, 0, 0, 0);
}

__device__ __forceinline__ void gl_lds16(const u16* g, u16* l) {
  __builtin_amdgcn_global_load_lds(
      (const __attribute__((address_space(1))) unsigned int*)g,
      (__attribute__((address_space(3))) unsigned int*)l, 16, 0, 0);
}

__device__ __forceinline__ u16 f2bf(float v) {
  __hip_bfloat16 h = __float2bfloat16(v);
  return __builtin_bit_cast(u16, h);
}

// bijective XCD swizzle (nwg % 8 == 0 for all our grids)
__device__ __forceinline__ int xcd_swz(int wid, int nwg) {
  return (wid & 7) * (nwg >> 3) + (wid >> 3);
}

// ---------------------------------------------------------------------------
// Pipelined 256x256 GEMM core. 512 threads / 8 waves (2M x 4N); per-wave
// output 128 rows x 64 virtual cols -> acc[8 m-frags][4 n-frags].
// BK=32, ring-3 LDS (3 x (A 256x32 + B 256x32) bf16 = 96 KB): stage tile
// t+2 while computing tile t; counted s_waitcnt vmcnt(4) at tile boundary
// (tile t+1 guaranteed complete, t+2's 4 loads stay in flight). XOR chunk
// swizzle kc ^= (row&3)^((row>>2)&3) applied to BOTH global_load_lds source
// and ds_read address (LDS stays linear) -> 2-way (free) bank pattern.
// A[row][k] row-major (lda); B[vcol][k] row-major (ldb). K % 32 == 0, K>=64.
// ---------------------------------------------------------------------------
__device__ __forceinline__ void gemm256(
    const u16* __restrict__ A, int lda,
    const u16* __restrict__ B, int ldb, int K,
    u16* lds, f32x4 (&acc)[8][4])
{
  const int t = threadIdx.x;
  const int l = t & 63;
  const int w = t >> 6;
  const int wm = w >> 2, wc = w & 3;

  // staging: thread t covers (row = p*128 + t/4, chunk = t%4) for A and B
  const int srow = t >> 2;
  const int skc = (t & 3) ^ ((srow & 3) ^ ((srow >> 2) & 3));
  const u16* gA0 = A + srow * lda + skc * 8;
  const u16* gB0 = B + srow * ldb + skc * 8;
  const u16* gA1 = gA0 + 128 * lda;
  const u16* gB1 = gB0 + 128 * ldb;

  // LDS dests (u16 offsets; wave-uniform base, HW adds lane*16B)
  const int dA0 = w * 512, dA1 = 4096 + w * 512;
  const int dB0 = 8192 + w * 512, dB1 = 12288 + w * 512;

  u16* s0 = lds;
  u16* s1 = lds + 16384;
  u16* s2 = lds + 32768;

  // fragment read offsets; kc swizzle reduces to a lane-only constant
  const int kcA = (l >> 4) ^ (l & 3) ^ ((l >> 2) & 3);
  const int aBase = (wm * 128 + (l & 15)) * 32 + kcA * 8;
  const int bBase = 8192 + (wc * 64 + (l & 15)) * 32 + kcA * 8;

  const int nt = K >> 5;

#define STAGE_TILE(slot, kt) do {                 \
    const int ko_ = (kt) * 32;                    \
    gl_lds16(gA0 + ko_, (slot) + dA0);            \
    gl_lds16(gA1 + ko_, (slot) + dA1);            \
    gl_lds16(gB0 + ko_, (slot) + dB0);            \
    gl_lds16(gB1 + ko_, (slot) + dB1);            \
  } while (0)

  STAGE_TILE(s0, 0);
  STAGE_TILE(s1, 1);
  asm volatile("s_waitcnt vmcnt(4)" ::: "memory");  // tile0 landed
  __builtin_amdgcn_s_barrier();
  __builtin_amdgcn_sched_barrier(0);

  for (int kt = 0; kt < nt; ++kt) {
    const bool more = (kt + 2 < nt);
    if (more) STAGE_TILE(s2, kt + 2);
    frag_t a[8];
#pragma unroll
    for (int fm = 0; fm < 8; ++fm)
      a[fm] = *(const frag_t*)(s0 + aBase + fm * 512);
    __builtin_amdgcn_s_setprio(1);
#pragma unroll
    for (int fn = 0; fn < 4; ++fn) {
      frag_t b = *(const frag_t*)(s0 + bBase + fn * 512);
#pragma unroll
      for (int fm = 0; fm < 8; ++fm)
        acc[fm][fn] = MFMA(a[fm], b, acc[fm][fn]);
    }
    __builtin_amdgcn_s_setprio(0);
    if (more) asm volatile("s_waitcnt vmcnt(4)" ::: "memory"); // t+1 ready
    else      asm volatile("s_waitcnt vmcnt(0)" ::: "memory"); // tail drain
    __builtin_amdgcn_s_barrier();
    __builtin_amdgcn_sched_barrier(0);
    u16* tmp = s0; s0 = s1; s1 = s2; s2 = tmp;
  }
#undef STAGE_TILE
}

// ---------------------------------------------------------------------------
// Kernel 1: weight repack f32 -> bf16 with gate/half interleaving.
// Wint[16 strips][256 vcols][1024]   vcol = wc*64 + gate*16 + c16,
//                                    actual col = s*64 + wc*16 + c16
// Rint[16 strips][256 vcols][128]    same vcol map, col within head
// upint[11 tiles][256 vcols][1024]   vcol = wc*64 + half*32 + c32,
//                                    actual col = tile*128 + wc*32 + c32
// dnp[1024][1408] k-padded zeros
// ---------------------------------------------------------------------------
__global__ __launch_bounds__(256) void prep_kernel(
    const float* __restrict__ Wi, const float* __restrict__ Wf,
    const float* __restrict__ Wz, const float* __restrict__ Wo,
    const float* __restrict__ Ri, const float* __restrict__ Rf,
    const float* __restrict__ Rz, const float* __restrict__ Ro,
    const float* __restrict__ upw, const float* __restrict__ dnw,
    u16* __restrict__ Wint, u16* __restrict__ Rint,
    u16* __restrict__ upint, u16* __restrict__ dnp)
{
  const int stride = gridDim.x * 256;
  for (int i = blockIdx.x * 256 + threadIdx.x; i < 9043968; i += stride) {
    if (i < 4194304) {
      const int s = i >> 18, v = (i >> 10) & 255, k = i & 1023;
      const int wc = v >> 6, gsel = (v >> 4) & 3, c16 = v & 15;
      const int srcRow = s * 64 + wc * 16 + c16;
      const float* W = (gsel == 0) ? Wi : (gsel == 1) ? Wf : (gsel == 2) ? Wz : Wo;
      Wint[i] = f2bf(W[srcRow * 1024 + k]);
    } else if (i < 4718592) {
      const int j = i - 4194304;
      const int s = j >> 15, v = (j >> 7) & 255, k = j & 127;
      const int wc = v >> 6, gsel = (v >> 4) & 3, c16 = v & 15;
      const int head = s >> 1;
      const int colInHead = (s & 1) * 64 + wc * 16 + c16;
      const float* R = (gsel == 0) ? Ri : (gsel == 1) ? Rf : (gsel == 2) ? Rz : Ro;
      Rint[j] = f2bf(R[head * 16384 + colInHead * 128 + k]);
    } else if (i < 7602176) {
      const int j = i - 4718592;
      const int vcol = j >> 10, k = j & 1023;
      const int tile = vcol >> 8, wc = (vcol >> 6) & 3;
      const int half = (vcol >> 5) & 1, c32 = vcol & 31;
      const int a = tile * 128 + wc * 32 + c32;
      upint[j] = (a < 1365) ? f2bf(upw[(half * 1365 + a) * 1024 + k]) : (u16)0;
    } else {
      const int j = i - 7602176;
      const int row = j / 1408, k = j - row * 1408;
      dnp[j] = (k < 1365) ? f2bf(dnw[row * 1365 + k]) : (u16)0;
    }
  }
}

// ---------------------------------------------------------------------------
// Kernel 2: LayerNorm(seq) -> x bf16 ; h0 -> bf16. One row per block.
// ---------------------------------------------------------------------------
__global__ __launch_bounds__(256) void ln_kernel(
    const float* __restrict__ seq, const float* __restrict__ h0,
    const float* __restrict__ lnw, const float* __restrict__ lnb,
    u16* __restrict__ xb, u16* __restrict__ h0b)
{
  const int row = blockIdx.x;
  const int t = threadIdx.x;
  const float4 v = ((const float4*)(seq + (size_t)row * 1024))[t];
  float s = v.x + v.y + v.z + v.w;
  float q = v.x * v.x + v.y * v.y + v.z * v.z + v.w * v.w;
#pragma unroll
  for (int o = 32; o >= 1; o >>= 1) { s += __shfl_xor(s, o); q += __shfl_xor(q, o); }
  __shared__ float sm[8];
  const int l = t & 63, w = t >> 6;
  if (l == 0) { sm[w] = s; sm[4 + w] = q; }
  __syncthreads();
  s = sm[0] + sm[1] + sm[2] + sm[3];
  q = sm[4] + sm[5] + sm[6] + sm[7];
  const float mu = s * (1.f / 1024.f);
  const float var = q * (1.f / 1024.f) - mu * mu;
  const float rstd = rsqrtf(var + 1e-5f);
  const float4 wv = ((const float4*)lnw)[t];
  const float4 bv = ((const float4*)lnb)[t];
  ushort4 o4;
  o4.x = f2bf((v.x - mu) * rstd * wv.x + bv.x);
  o4.y = f2bf((v.y - mu) * rstd * wv.y + bv.y);
  o4.z = f2bf((v.z - mu) * rstd * wv.z + bv.z);
  o4.w = f2bf((v.w - mu) * rstd * wv.w + bv.w);
  ((ushort4*)(xb + (size_t)row * 1024))[t] = o4;
  const float4 h = ((const float4*)(h0 + (size_t)row * 1024))[t];
  ushort4 h4;
  h4.x = f2bf(h.x); h4.y = f2bf(h.y); h4.z = f2bf(h.z); h4.w = f2bf(h.w);
  ((ushort4*)(h0b + (size_t)row * 1024))[t] = h4;
}

// ---------------------------------------------------------------------------
// Kernel 3: fused 4-gate GEMM (+recurrent block-diag) + sLSTM pointwise.
// Block: 256 rows x strip(64 actual cols) x 4 gates (virtual N=256).
// Wave owns 128 rows x 16 actual cols x 4 gates -> pointwise in-register.
// ---------------------------------------------------------------------------
__global__ __launch_bounds__(512, 2) void gate_kernel(
    const u16* __restrict__ xb, const u16* __restrict__ h0b,
    const u16* __restrict__ Wint, const u16* __restrict__ Rint,
    const float* __restrict__ bi, const float* __restrict__ bfv,
    const float* __restrict__ bz, const float* __restrict__ bo,
    const float* __restrict__ c0, const float* __restrict__ n0i,
    const float* __restrict__ m0,
    float* __restrict__ oc, float* __restrict__ on,
    float* __restrict__ oh, float* __restrict__ om)
{
  __shared__ __align__(16) u16 lds[49152];
  const int wid = xcd_swz(blockIdx.x, 1024);
  const int s = wid & 15;           // 64-col strip
  const int m0r = (wid >> 4) * 256;
  f32x4 acc[8][4] = {};
  // x @ W^T (K=1024)
  gemm256(xb + (size_t)m0r * 1024, 1024, Wint + s * 262144, 1024, 1024, lds, acc);
  // + blockdiag(h0 @ R^T) (K=128; strip lies entirely in head s>>1)
  const int head = s >> 1;
  gemm256(h0b + (size_t)m0r * 1024 + head * 128, 1024,
          Rint + s * 32768, 128, 128, lds, acc);

  const int t = threadIdx.x, l = t & 63, w = t >> 6, wm = w >> 2, wc = w & 3;
  const int cc = s * 64 + wc * 16 + (l & 15);
  const float biv = bi[cc], bfvv = bfv[cc], bzv = bz[cc], bov = bo[cc];
#pragma unroll
  for (int fm = 0; fm < 8; ++fm) {
    const int rbase = m0r + wm * 128 + fm * 16 + (l >> 4) * 4;
#pragma unroll
    for (int r = 0; r < 4; ++r) {
      const size_t idx = (size_t)(rbase + r) * 1024 + cc;
      const float it = acc[fm][0][r] + biv;
      const float ft = acc[fm][1][r] + bfvv;
      const float zt = acc[fm][2][r] + bzv;
      const float ot = acc[fm][3][r] + bov;
      const float mp = m0[idx];
      const float mt = fmaxf(ft + mp, it);
      const float ie = __expf(it - mt);
      const float fe = __expf(ft - mt + mp);
      const float ct = fe * c0[idx] + ie * tanhf(zt);
      const float nt = fe * n0i[idx] + ie;
      const float ht = (ct / nt) / (1.f + __expf(-ot));
      oc[idx] = ct; on[idx] = nt; oh[idx] = ht; om[idx] = mt;
    }
  }
}

// ---------------------------------------------------------------------------
// Kernel 4: GroupNorm over heads (128 ch / group), one wave per group -> bf16
// ---------------------------------------------------------------------------
__global__ __launch_bounds__(256) void gn_kernel(
    const float* __restrict__ h, const float* __restrict__ gw,
    const float* __restrict__ gb, u16* __restrict__ gnb)
{
  const int t = threadIdx.x, l = t & 63, w = t >> 6;
  for (int grp = blockIdx.x * 4 + w; grp < 16384 * 8; grp += gridDim.x * 4) {
    const int b = grp >> 3, hd = grp & 7;
    const float2 v = ((const float2*)(h + b * 1024 + hd * 128))[l];
    float s = v.x + v.y, q = v.x * v.x + v.y * v.y;
#pragma unroll
    for (int o = 32; o >= 1; o >>= 1) { s += __shfl_xor(s, o); q += __shfl_xor(q, o); }
    const float mu = s * (1.f / 128.f);
    const float var = q * (1.f / 128.f) - mu * mu;
    const float rstd = rsqrtf(var + 1e-5f);
    const float2 wv = ((const float2*)(gw + hd * 128))[l];
    const float2 bv = ((const float2*)(gb + hd * 128))[l];
    ushort2 o2;
    o2.x = f2bf((v.x - mu) * rstd * wv.x + bv.x);
    o2.y = f2bf((v.y - mu) * rstd * wv.y + bv.y);
    ((ushort2*)(gnb + b * 1024 + hd * 128))[l] = o2;
  }
}

// ---------------------------------------------------------------------------
// Kernel 5: up-proj; halves interleaved so (u1,u2) pair in-wave; GELU-GLU.
// ---------------------------------------------------------------------------
__global__ __launch_bounds__(512, 2) void up_kernel(
    const u16* __restrict__ gnb, const u16* __restrict__ upint,
    const float* __restrict__ upb, u16* __restrict__ g)
{
  __shared__ __align__(16) u16 lds[49152];
  const int wid = xcd_swz(blockIdx.x, 704);
  const int vt = wid % 11, mt = wid / 11;
  const int m0r = mt * 256;
  f32x4 acc[8][4] = {};
  gemm256(gnb + (size_t)m0r * 1024, 1024, upint + vt * 262144, 1024, 1024,
          lds, acc);
  const int t = threadIdx.x, l = t & 63, w = t >> 6, wm = w >> 2, wc = w & 3;
#pragma unroll
  for (int fm = 0; fm < 8; ++fm) {
    const int rbase = m0r + wm * 128 + fm * 16 + (l >> 4) * 4;
#pragma unroll
    for (int fn = 0; fn < 2; ++fn) {
      const int a = vt * 128 + wc * 32 + fn * 16 + (l & 15);
      const float b1 = (a < 1365) ? upb[a] : 0.f;
      const float b2 = (a < 1365) ? upb[1365 + a] : 0.f;
#pragma unroll
      for (int r = 0; r < 4; ++r) {
        const float u1 = acc[fm][fn][r] + b1;
        const float u2 = acc[fm][fn + 2][r] + b2;
        const float ge = 0.5f * u2 * (1.f + erff(u2 * 0.70710678118654752f));
        g[(size_t)(rbase + r) * 1408 + a] = f2bf(u1 + ge);
      }
    }
  }
}

// ---------------------------------------------------------------------------
// Kernel 6: down-proj (K=1408, zero-padded) + bias + residual -> d_out
// ---------------------------------------------------------------------------
__global__ __launch_bounds__(512, 2) void down_kernel(
    const u16* __restrict__ g, const u16* __restrict__ dnp,
    const float* __restrict__ dnb, const float* __restrict__ seq,
    float* __restrict__ out)
{
  __shared__ __align__(16) u16 lds[49152];
  const int wid = xcd_swz(blockIdx.x, 256);
  const int nc = (wid & 3) * 256;
  const int m0r = (wid >> 2) * 256;
  f32x4 acc[8][4] = {};
  gemm256(g + (size_t)m0r * 1408, 1408, dnp + nc * 1408, 1408, 1408, lds, acc);
  const int t = threadIdx.x, l = t & 63, w = t >> 6, wm = w >> 2, wc = w & 3;
#pragma unroll
  for (int fm = 0; fm < 8; ++fm) {
    const int rbase = m0r + wm * 128 + fm * 16 + (l >> 4) * 4;
#pragma unroll
    for (int fn = 0; fn < 4; ++fn) {
      const int cc = nc + wc * 64 + fn * 16 + (l & 15);
      const float bb = dnb[cc];
#pragma unroll
      for (int r = 0; r < 4; ++r) {
        const size_t idx = (size_t)(rbase + r) * 1024 + cc;
        out[idx] = acc[fm][fn][r] + bb + seq[idx];
      }
    }
  }
}

// ---------------------------------------------------------------------------
extern "C" void kernel_launch(void* const* d_in, const int* in_sizes, int n_in,
                              void* d_out, int out_size, void* d_ws, size_t ws_size,
                              hipStream_t stream) {
  const float* seq = (const float*)d_in[0];
  const float* c0  = (const float*)d_in[1];
  const float* n0i = (const float*)d_in[2];
  const float* h0  = (const float*)d_in[3];
  const float* m0  = (const float*)d_in[4];
  const float* lnw = (const float*)d_in[5];
  const float* lnb = (const float*)d_in[6];
  const float* Wz  = (const float*)d_in[7];
  const float* bz  = (const float*)d_in[8];
  const float* Wi  = (const float*)d_in[9];
  const float* bi  = (const float*)d_in[10];
  const float* Wo  = (const float*)d_in[11];
  const float* bo  = (const float*)d_in[12];
  const float* Wf  = (const float*)d_in[13];
  const float* bf_ = (const float*)d_in[14];
  const float* Rz  = (const float*)d_in[15];
  const float* Ri  = (const float*)d_in[16];
  const float* Ro  = (const float*)d_in[17];
  const float* Rf  = (const float*)d_in[18];
  const float* gw  = (const float*)d_in[19];
  const float* gb  = (const float*)d_in[20];
  const float* upw = (const float*)d_in[21];
  const float* upb = (const float*)d_in[22];
  const float* dnw = (const float*)d_in[23];
  const float* dnb = (const float*)d_in[24];

  char* ws = (char*)d_ws;
  u16* xb   = (u16*)(ws);              // 33,554,432 B (reused for gn output)
  u16* h0b  = (u16*)(ws + 33554432);   // 33,554,432 B
  u16* Wint = (u16*)(ws + 67108864);   //  8,388,608 B
  u16* Rint = (u16*)(ws + 75497472);   //  1,048,576 B
  u16* upc  = (u16*)(ws + 76546048);   //  5,767,168 B
  u16* dnp  = (u16*)(ws + 82313216);   //  2,883,584 B
  u16* g    = (u16*)(ws + 85196800);   // 46,137,344 B

  float* out = (float*)d_out;
  float* oc = out + 16777216;
  float* on = out + 2 * 16777216;
  float* oh = out + 3 * 16777216;
  float* om = out + 4 * 16777216;

  prep_kernel<<<dim3(2048), dim3(256), 0, stream>>>(
      Wi, Wf, Wz, Wo, Ri, Rf, Rz, Ro, upw, dnw, Wint, Rint, upc, dnp);
  ln_kernel<<<dim3(16384), dim3(256), 0, stream>>>(seq, h0, lnw, lnb, xb, h0b);
  gate_kernel<<<dim3(1024), dim3(512), 0, stream>>>(
      xb, h0b, Wint, Rint, bi, bf_, bz, bo, c0, n0i, m0, oc, on, oh, om);
  gn_kernel<<<dim3(2048), dim3(256), 0, stream>>>(oh, gw, gb, xb);
  up_kernel<<<dim3(704), dim3(512), 0, stream>>>(xb, upc, upb, g);
  down_kernel<<<dim3(256), dim3(512), 0, stream>>>(g, dnp, dnb, seq, out);
}

// Round 4
// 505.878 us; speedup vs baseline: 1.5023x; 1.0552x over previous
//
#include <hip/hip_runtime.h>
#include <hip/hip_bf16.h>
#include <cstdint>
#include <type_traits>

typedef __attribute__((ext_vector_type(8))) __bf16 bf16x8;
typedef __attribute__((ext_vector_type(8))) short short8;
typedef __attribute__((ext_vector_type(4))) float f32x4;
using u16 = unsigned short;

// ---- MFMA fragment-type autodetect ----
template <typename T, typename = void> struct mfma_ok : std::false_type {};
template <typename T>
struct mfma_ok<T, std::void_t<decltype(__builtin_amdgcn_mfma_f32_16x16x32_bf16(
    std::declval<T>(), std::declval<T>(), std::declval<f32x4>(), 0, 0, 0))>>
    : std::true_type {};
using frag_t = std::conditional_t<mfma_ok<bf16x8>::value, bf16x8, short8>;
static_assert(sizeof(frag_t) == 16, "frag must be 4 VGPRs");

template <typename T>
__device__ __forceinline__ f32x4 MFMA(T a, T b, f32x4 c) {
  return __builtin_amdgcn_mfma_f32_16x16x32_bf16(a, b, c, 0, 0, 0);
}

__device__ __forceinline__ void gl_lds16(const u16* g, u16* l) {
  __builtin_amdgcn_global_load_lds(
      (const __attribute__((address_space(1))) unsigned int*)g,
      (__attribute__((address_space(3))) unsigned int*)l, 16, 0, 0);
}

__device__ __forceinline__ u16 f2bf(float v) {
  __hip_bfloat16 h = __float2bfloat16(v);
  return __builtin_bit_cast(u16, h);
}

// bijective XCD swizzle (nwg % 8 == 0 for all our grids)
__device__ __forceinline__ int xcd_swz(int wid, int nwg) {
  return (wid & 7) * (nwg >> 3) + (wid >> 3);
}

// ---------------------------------------------------------------------------
// GEMM core v4: 256x256(virtual) tile, BK=64, 512 threads / 8 waves (2M x 4N).
// Per-wave output 128 rows x 64 vcols -> acc[8][4]. LDS: 2 buffers x 64KB
// (A 256x64 + B 256x64 bf16). Schedule per K-tile: stage next tile (8 x
// global_load_lds, 1 tile = 2483 MFMA-cyc/CU >> 900 cyc HBM latency), then
// 2 k-frag phases of {12 ds_read_b128 + 32 MFMA}, then vmcnt(0)+barrier
// (single drain per tile, lands mid-tile so ~free).
// Bank swizzle: LDS[row][p] holds global chunk p^(row&7); applied to the
// global source addr (LDS linear for gl_lds) and the ds_read offset.
// A[row][k] row-major (lda); B[vcol][k] row-major (ldb). K%64==0.
// ---------------------------------------------------------------------------
__device__ __forceinline__ void gemm256(
    const u16* __restrict__ A, int lda,
    const u16* __restrict__ B, int ldb, int K,
    u16* lds, f32x4 (&acc)[8][4])
{
  const int t = threadIdx.x;
  const int l = t & 63;
  const int w = t >> 6;
  const int wm = w >> 2, wc = w & 3;

  // staging: instr j covers rows j*64 + (t>>3); per-thread src chunk
  const int sc = (t & 7) ^ ((t >> 3) & 7);
  const u16* gA = A + (t >> 3) * lda + sc * 8;
  const u16* gB = B + (t >> 3) * ldb + sc * 8;

#define STAGE(buf, kt) do {                                   \
    const u16* a_ = gA + (kt) * 64;                           \
    const u16* b_ = gB + (kt) * 64;                           \
    u16* s_ = (buf);                                          \
    gl_lds16(a_,             s_ + w * 512);                   \
    gl_lds16(a_ +  64 * lda, s_ +  4096 + w * 512);           \
    gl_lds16(a_ + 128 * lda, s_ +  8192 + w * 512);           \
    gl_lds16(a_ + 192 * lda, s_ + 12288 + w * 512);           \
    gl_lds16(b_,             s_ + 16384 + w * 512);           \
    gl_lds16(b_ +  64 * ldb, s_ + 20480 + w * 512);           \
    gl_lds16(b_ + 128 * ldb, s_ + 24576 + w * 512);           \
    gl_lds16(b_ + 192 * ldb, s_ + 28672 + w * 512);           \
  } while (0)

  const int lr = l & 15;
  const int lk = l >> 4;
  const int lx = l & 7;
  const int pk0 = ((0 + lk) ^ lx) * 8;
  const int pk1 = ((4 + lk) ^ lx) * 8;
  const int arow0 = (wm * 128 + lr) * 64;
  const int brow0 = 16384 + (wc * 64 + lr) * 64;

  const int nt = K >> 6;

  STAGE(lds, 0);
  asm volatile("s_waitcnt vmcnt(0)" ::: "memory");
  __builtin_amdgcn_s_barrier();

  for (int kt = 0; kt < nt; ++kt) {
    u16* cur = lds + (kt & 1) * 32768;
    u16* nxt = lds + ((kt + 1) & 1) * 32768;
    if (kt + 1 < nt) STAGE(nxt, kt + 1);
    __builtin_amdgcn_sched_barrier(0);
#pragma unroll
    for (int kf = 0; kf < 2; ++kf) {
      const int pk = kf ? pk1 : pk0;
      frag_t a[8], b[4];
#pragma unroll
      for (int fm = 0; fm < 8; ++fm)
        a[fm] = *(const frag_t*)(cur + arow0 + fm * 1024 + pk);
#pragma unroll
      for (int fn = 0; fn < 4; ++fn)
        b[fn] = *(const frag_t*)(cur + brow0 + fn * 1024 + pk);
      __builtin_amdgcn_s_setprio(1);
#pragma unroll
      for (int fn = 0; fn < 4; ++fn)
#pragma unroll
        for (int fm = 0; fm < 8; ++fm)
          acc[fm][fn] = MFMA(a[fm], b[fn], acc[fm][fn]);
      __builtin_amdgcn_s_setprio(0);
    }
    asm volatile("s_waitcnt vmcnt(0)" ::: "memory");
    __builtin_amdgcn_s_barrier();
  }
#undef STAGE
}

// ---------------------------------------------------------------------------
// Kernel 1: weight repack f32 -> bf16 with gate/half interleaving.
// Wint[16 strips][256 vcols][1024]   vcol = wc*64 + gate*16 + c16,
//                                    actual col = s*64 + wc*16 + c16
// Rint[16 strips][256 vcols][128]    same vcol map, col within head
// upint[11 tiles][256 vcols][1024]   vcol = wc*64 + half*32 + c32,
//                                    actual col = tile*128 + wc*32 + c32
// dnp[1024][1408] k-padded zeros
// ---------------------------------------------------------------------------
__global__ __launch_bounds__(256) void prep_kernel(
    const float* __restrict__ Wi, const float* __restrict__ Wf,
    const float* __restrict__ Wz, const float* __restrict__ Wo,
    const float* __restrict__ Ri, const float* __restrict__ Rf,
    const float* __restrict__ Rz, const float* __restrict__ Ro,
    const float* __restrict__ upw, const float* __restrict__ dnw,
    u16* __restrict__ Wint, u16* __restrict__ Rint,
    u16* __restrict__ upint, u16* __restrict__ dnp)
{
  const int stride = gridDim.x * 256;
  for (int i = blockIdx.x * 256 + threadIdx.x; i < 9043968; i += stride) {
    if (i < 4194304) {
      const int s = i >> 18, v = (i >> 10) & 255, k = i & 1023;
      const int wc = v >> 6, gsel = (v >> 4) & 3, c16 = v & 15;
      const int srcRow = s * 64 + wc * 16 + c16;
      const float* W = (gsel == 0) ? Wi : (gsel == 1) ? Wf : (gsel == 2) ? Wz : Wo;
      Wint[i] = f2bf(W[srcRow * 1024 + k]);
    } else if (i < 4718592) {
      const int j = i - 4194304;
      const int s = j >> 15, v = (j >> 7) & 255, k = j & 127;
      const int wc = v >> 6, gsel = (v >> 4) & 3, c16 = v & 15;
      const int head = s >> 1;
      const int colInHead = (s & 1) * 64 + wc * 16 + c16;
      const float* R = (gsel == 0) ? Ri : (gsel == 1) ? Rf : (gsel == 2) ? Rz : Ro;
      Rint[j] = f2bf(R[head * 16384 + colInHead * 128 + k]);
    } else if (i < 7602176) {
      const int j = i - 4718592;
      const int vcol = j >> 10, k = j & 1023;
      const int tile = vcol >> 8, wc = (vcol >> 6) & 3;
      const int half = (vcol >> 5) & 1, c32 = vcol & 31;
      const int a = tile * 128 + wc * 32 + c32;
      upint[j] = (a < 1365) ? f2bf(upw[(half * 1365 + a) * 1024 + k]) : (u16)0;
    } else {
      const int j = i - 7602176;
      const int row = j / 1408, k = j - row * 1408;
      dnp[j] = (k < 1365) ? f2bf(dnw[row * 1365 + k]) : (u16)0;
    }
  }
}

// ---------------------------------------------------------------------------
// Kernel 2: LayerNorm(seq) -> x bf16 ; h0 -> bf16. One row per block.
// ---------------------------------------------------------------------------
__global__ __launch_bounds__(256) void ln_kernel(
    const float* __restrict__ seq, const float* __restrict__ h0,
    const float* __restrict__ lnw, const float* __restrict__ lnb,
    u16* __restrict__ xb, u16* __restrict__ h0b)
{
  const int row = blockIdx.x;
  const int t = threadIdx.x;
  const float4 v = ((const float4*)(seq + (size_t)row * 1024))[t];
  float s = v.x + v.y + v.z + v.w;
  float q = v.x * v.x + v.y * v.y + v.z * v.z + v.w * v.w;
#pragma unroll
  for (int o = 32; o >= 1; o >>= 1) { s += __shfl_xor(s, o); q += __shfl_xor(q, o); }
  __shared__ float sm[8];
  const int l = t & 63, w = t >> 6;
  if (l == 0) { sm[w] = s; sm[4 + w] = q; }
  __syncthreads();
  s = sm[0] + sm[1] + sm[2] + sm[3];
  q = sm[4] + sm[5] + sm[6] + sm[7];
  const float mu = s * (1.f / 1024.f);
  const float var = q * (1.f / 1024.f) - mu * mu;
  const float rstd = rsqrtf(var + 1e-5f);
  const float4 wv = ((const float4*)lnw)[t];
  const float4 bv = ((const float4*)lnb)[t];
  ushort4 o4;
  o4.x = f2bf((v.x - mu) * rstd * wv.x + bv.x);
  o4.y = f2bf((v.y - mu) * rstd * wv.y + bv.y);
  o4.z = f2bf((v.z - mu) * rstd * wv.z + bv.z);
  o4.w = f2bf((v.w - mu) * rstd * wv.w + bv.w);
  ((ushort4*)(xb + (size_t)row * 1024))[t] = o4;
  const float4 h = ((const float4*)(h0 + (size_t)row * 1024))[t];
  ushort4 h4;
  h4.x = f2bf(h.x); h4.y = f2bf(h.y); h4.z = f2bf(h.z); h4.w = f2bf(h.w);
  ((ushort4*)(h0b + (size_t)row * 1024))[t] = h4;
}

// ---------------------------------------------------------------------------
// Kernel 3: fused 4-gate GEMM (+recurrent block-diag) + sLSTM pointwise.
// Block: 256 rows x strip(64 actual cols) x 4 gates (virtual N=256).
// Wave owns 128 rows x 16 actual cols x 4 gates -> pointwise in-register.
// ---------------------------------------------------------------------------
__global__ __launch_bounds__(512, 2) void gate_kernel(
    const u16* __restrict__ xb, const u16* __restrict__ h0b,
    const u16* __restrict__ Wint, const u16* __restrict__ Rint,
    const float* __restrict__ bi, const float* __restrict__ bfv,
    const float* __restrict__ bz, const float* __restrict__ bo,
    const float* __restrict__ c0, const float* __restrict__ n0i,
    const float* __restrict__ m0,
    float* __restrict__ oc, float* __restrict__ on,
    float* __restrict__ oh, float* __restrict__ om)
{
  __shared__ __align__(16) u16 lds[65536];
  const int wid = xcd_swz(blockIdx.x, 1024);
  const int s = wid & 15;           // 64-col strip
  const int m0r = (wid >> 4) * 256;
  f32x4 acc[8][4] = {};
  // x @ W^T (K=1024)
  gemm256(xb + (size_t)m0r * 1024, 1024, Wint + s * 262144, 1024, 1024, lds, acc);
  // + blockdiag(h0 @ R^T) (K=128; strip lies entirely in head s>>1)
  const int head = s >> 1;
  gemm256(h0b + (size_t)m0r * 1024 + head * 128, 1024,
          Rint + s * 32768, 128, 128, lds, acc);

  const int t = threadIdx.x, l = t & 63, w = t >> 6, wm = w >> 2, wc = w & 3;
  const int cc = s * 64 + wc * 16 + (l & 15);
  const float biv = bi[cc], bfvv = bfv[cc], bzv = bz[cc], bov = bo[cc];
#pragma unroll
  for (int fm = 0; fm < 8; ++fm) {
    const int rbase = m0r + wm * 128 + fm * 16 + (l >> 4) * 4;
#pragma unroll
    for (int r = 0; r < 4; ++r) {
      const size_t idx = (size_t)(rbase + r) * 1024 + cc;
      const float it = acc[fm][0][r] + biv;
      const float ft = acc[fm][1][r] + bfvv;
      const float zt = acc[fm][2][r] + bzv;
      const float ot = acc[fm][3][r] + bov;
      const float mp = m0[idx];
      const float mt = fmaxf(ft + mp, it);
      const float ie = __expf(it - mt);
      const float fe = __expf(ft - mt + mp);
      const float ct = fe * c0[idx] + ie * tanhf(zt);
      const float nt = fe * n0i[idx] + ie;
      const float ht = (ct / nt) / (1.f + __expf(-ot));
      oc[idx] = ct; on[idx] = nt; oh[idx] = ht; om[idx] = mt;
    }
  }
}

// ---------------------------------------------------------------------------
// Kernel 4: GroupNorm over heads (128 ch / group), one wave per group -> bf16
// ---------------------------------------------------------------------------
__global__ __launch_bounds__(256) void gn_kernel(
    const float* __restrict__ h, const float* __restrict__ gw,
    const float* __restrict__ gb, u16* __restrict__ gnb)
{
  const int t = threadIdx.x, l = t & 63, w = t >> 6;
  for (int grp = blockIdx.x * 4 + w; grp < 16384 * 8; grp += gridDim.x * 4) {
    const int b = grp >> 3, hd = grp & 7;
    const float2 v = ((const float2*)(h + b * 1024 + hd * 128))[l];
    float s = v.x + v.y, q = v.x * v.x + v.y * v.y;
#pragma unroll
    for (int o = 32; o >= 1; o >>= 1) { s += __shfl_xor(s, o); q += __shfl_xor(q, o); }
    const float mu = s * (1.f / 128.f);
    const float var = q * (1.f / 128.f) - mu * mu;
    const float rstd = rsqrtf(var + 1e-5f);
    const float2 wv = ((const float2*)(gw + hd * 128))[l];
    const float2 bv = ((const float2*)(gb + hd * 128))[l];
    ushort2 o2;
    o2.x = f2bf((v.x - mu) * rstd * wv.x + bv.x);
    o2.y = f2bf((v.y - mu) * rstd * wv.y + bv.y);
    ((ushort2*)(gnb + b * 1024 + hd * 128))[l] = o2;
  }
}

// ---------------------------------------------------------------------------
// Kernel 5: up-proj; halves interleaved so (u1,u2) pair in-wave; GELU-GLU.
// ---------------------------------------------------------------------------
__global__ __launch_bounds__(512, 2) void up_kernel(
    const u16* __restrict__ gnb, const u16* __restrict__ upint,
    const float* __restrict__ upb, u16* __restrict__ g)
{
  __shared__ __align__(16) u16 lds[65536];
  const int wid = xcd_swz(blockIdx.x, 704);
  const int vt = wid % 11, mt = wid / 11;
  const int m0r = mt * 256;
  f32x4 acc[8][4] = {};
  gemm256(gnb + (size_t)m0r * 1024, 1024, upint + vt * 262144, 1024, 1024,
          lds, acc);
  const int t = threadIdx.x, l = t & 63, w = t >> 6, wm = w >> 2, wc = w & 3;
#pragma unroll
  for (int fm = 0; fm < 8; ++fm) {
    const int rbase = m0r + wm * 128 + fm * 16 + (l >> 4) * 4;
#pragma unroll
    for (int fn = 0; fn < 2; ++fn) {
      const int a = vt * 128 + wc * 32 + fn * 16 + (l & 15);
      const float b1 = (a < 1365) ? upb[a] : 0.f;
      const float b2 = (a < 1365) ? upb[1365 + a] : 0.f;
#pragma unroll
      for (int r = 0; r < 4; ++r) {
        const float u1 = acc[fm][fn][r] + b1;
        const float u2 = acc[fm][fn + 2][r] + b2;
        const float ge = 0.5f * u2 * (1.f + erff(u2 * 0.70710678118654752f));
        g[(size_t)(rbase + r) * 1408 + a] = f2bf(u1 + ge);
      }
    }
  }
}

// ---------------------------------------------------------------------------
// Kernel 6: down-proj (K=1408, zero-padded) + bias + residual -> d_out
// ---------------------------------------------------------------------------
__global__ __launch_bounds__(512, 2) void down_kernel(
    const u16* __restrict__ g, const u16* __restrict__ dnp,
    const float* __restrict__ dnb, const float* __restrict__ seq,
    float* __restrict__ out)
{
  __shared__ __align__(16) u16 lds[65536];
  const int wid = xcd_swz(blockIdx.x, 256);
  const int nc = (wid & 3) * 256;
  const int m0r = (wid >> 2) * 256;
  f32x4 acc[8][4] = {};
  gemm256(g + (size_t)m0r * 1408, 1408, dnp + nc * 1408, 1408, 1408, lds, acc);
  const int t = threadIdx.x, l = t & 63, w = t >> 6, wm = w >> 2, wc = w & 3;
#pragma unroll
  for (int fm = 0; fm < 8; ++fm) {
    const int rbase = m0r + wm * 128 + fm * 16 + (l >> 4) * 4;
#pragma unroll
    for (int fn = 0; fn < 4; ++fn) {
      const int cc = nc + wc * 64 + fn * 16 + (l & 15);
      const float bb = dnb[cc];
#pragma unroll
      for (int r = 0; r < 4; ++r) {
        const size_t idx = (size_t)(rbase + r) * 1024 + cc;
        out[idx] = acc[fm][fn][r] + bb + seq[idx];
      }
    }
  }
}

// ---------------------------------------------------------------------------
extern "C" void kernel_launch(void* const* d_in, const int* in_sizes, int n_in,
                              void* d_out, int out_size, void* d_ws, size_t ws_size,
                              hipStream_t stream) {
  const float* seq = (const float*)d_in[0];
  const float* c0  = (const float*)d_in[1];
  const float* n0i = (const float*)d_in[2];
  const float* h0  = (const float*)d_in[3];
  const float* m0  = (const float*)d_in[4];
  const float* lnw = (const float*)d_in[5];
  const float* lnb = (const float*)d_in[6];
  const float* Wz  = (const float*)d_in[7];
  const float* bz  = (const float*)d_in[8];
  const float* Wi  = (const float*)d_in[9];
  const float* bi  = (const float*)d_in[10];
  const float* Wo  = (const float*)d_in[11];
  const float* bo  = (const float*)d_in[12];
  const float* Wf  = (const float*)d_in[13];
  const float* bf_ = (const float*)d_in[14];
  const float* Rz  = (const float*)d_in[15];
  const float* Ri  = (const float*)d_in[16];
  const float* Ro  = (const float*)d_in[17];
  const float* Rf  = (const float*)d_in[18];
  const float* gw  = (const float*)d_in[19];
  const float* gb  = (const float*)d_in[20];
  const float* upw = (const float*)d_in[21];
  const float* upb = (const float*)d_in[22];
  const float* dnw = (const float*)d_in[23];
  const float* dnb = (const float*)d_in[24];

  char* ws = (char*)d_ws;
  u16* xb   = (u16*)(ws);              // 33,554,432 B (reused for gn output)
  u16* h0b  = (u16*)(ws + 33554432);   // 33,554,432 B
  u16* Wint = (u16*)(ws + 67108864);   //  8,388,608 B
  u16* Rint = (u16*)(ws + 75497472);   //  1,048,576 B
  u16* upc  = (u16*)(ws + 76546048);   //  5,767,168 B
  u16* dnp  = (u16*)(ws + 82313216);   //  2,883,584 B
  u16* g    = (u16*)(ws + 85196800);   // 46,137,344 B

  float* out = (float*)d_out;
  float* oc = out + 16777216;
  float* on = out + 2 * 16777216;
  float* oh = out + 3 * 16777216;
  float* om = out + 4 * 16777216;

  prep_kernel<<<dim3(2048), dim3(256), 0, stream>>>(
      Wi, Wf, Wz, Wo, Ri, Rf, Rz, Ro, upw, dnw, Wint, Rint, upc, dnp);
  ln_kernel<<<dim3(16384), dim3(256), 0, stream>>>(seq, h0, lnw, lnb, xb, h0b);
  gate_kernel<<<dim3(1024), dim3(512), 0, stream>>>(
      xb, h0b, Wint, Rint, bi, bf_, bz, bo, c0, n0i, m0, oc, on, oh, om);
  gn_kernel<<<dim3(2048), dim3(256), 0, stream>>>(oh, gw, gb, xb);
  up_kernel<<<dim3(704), dim3(512), 0, stream>>>(xb, upc, upb, g);
  down_kernel<<<dim3(256), dim3(512), 0, stream>>>(g, dnp, dnb, seq, out);
}